// Round 3
// baseline (532.131 us; speedup 1.0000x reference)
//
#include <hip/hip_runtime.h>
#include <math.h>

#define NIMG 32
#define CDIM 256
#define KCL  64
#define SPIX 4096

// ---------------- K0: transpose conv_w (K x C) -> wT (C x K) ----------------
__global__ __launch_bounds__(256) void k_wt(const float* __restrict__ w, float* __restrict__ wT) {
    int g = blockIdx.x * 256 + threadIdx.x;   // g = k*CDIM + c
    if (g < KCL * CDIM) {
        int k = g / CDIM, c = g % CDIM;
        wT[c * KCL + k] = w[g];
    }
}

// ---------------- K1: fused norm + logits + softmax + asum ------------------
// grid 2048 = (n, 64 chunks of 64 px), 256 threads = (kg = tid>>6, p = tid&63)
// Each thread: acc[16] only (round 1/2: acc[64] -> allocator spilled to
// scratch at VGPR=52 regardless of launch_bounds -> 170us latency-bound).
__global__ __launch_bounds__(256) void k_logits(const float* __restrict__ x,
                                                const float* __restrict__ wT,
                                                const float* __restrict__ b,
                                                float* __restrict__ aT,
                                                float* __restrict__ inv_norm,
                                                float* __restrict__ asum_part) {
    int blk = blockIdx.x;
    int n = blk >> 6, chunk = blk & 63;
    int tid = threadIdx.x;
    int kg = tid >> 6, p = tid & 63;     // wave-uniform kg; lane = pixel
    int s = chunk * 64 + p;
    const float* xp = x + ((size_t)n * CDIM) * SPIX + s;
    const float4* wt4 = (const float4*)wT;       // [c][16 float4]

    float acc[16];
    #pragma unroll
    for (int i = 0; i < 16; i++) acc[i] = 0.f;
    float nrm = 0.f;

    for (int c = 0; c < CDIM; c++) {
        float xv = xp[(size_t)c * SPIX];         // coalesced; L1-shared by 4 waves
        nrm = fmaf(xv, xv, nrm);
        const float4* wc = wt4 + c * 16 + kg * 4;  // wave-uniform address
        #pragma unroll
        for (int j = 0; j < 4; j++) {
            float4 wv = wc[j];
            acc[4*j+0] = fmaf(wv.x, xv, acc[4*j+0]);
            acc[4*j+1] = fmaf(wv.y, xv, acc[4*j+1]);
            acc[4*j+2] = fmaf(wv.z, xv, acc[4*j+2]);
            acc[4*j+3] = fmaf(wv.w, xv, acc[4*j+3]);
        }
    }

    float invn = 1.0f / fmaxf(sqrtf(nrm), 1e-12f);
    if (kg == 0) inv_norm[n * SPIX + s] = invn;

    // logits = acc*invn + b ; softmax across the 4 k-groups via LDS
    const float4* b4 = (const float4*)b + kg * 4;
    float lg[16];
    float m = -1e30f;
    #pragma unroll
    for (int j = 0; j < 4; j++) {
        float4 bv = b4[j];
        lg[4*j+0] = fmaf(acc[4*j+0], invn, bv.x);
        lg[4*j+1] = fmaf(acc[4*j+1], invn, bv.y);
        lg[4*j+2] = fmaf(acc[4*j+2], invn, bv.z);
        lg[4*j+3] = fmaf(acc[4*j+3], invn, bv.w);
    }
    #pragma unroll
    for (int i = 0; i < 16; i++) m = fmaxf(m, lg[i]);

    __shared__ float red[4 * 64];
    red[kg * 64 + p] = m;
    __syncthreads();
    m = fmaxf(fmaxf(red[p], red[64 + p]), fmaxf(red[128 + p], red[192 + p]));

    float ssum = 0.f;
    #pragma unroll
    for (int i = 0; i < 16; i++) { float e = __expf(lg[i] - m); acc[i] = e; ssum += e; }
    __syncthreads();
    red[kg * 64 + p] = ssum;
    __syncthreads();
    ssum = red[p] + red[64 + p] + red[128 + p] + red[192 + p];
    float r = 1.0f / ssum;
    #pragma unroll
    for (int i = 0; i < 16; i++) acc[i] *= r;

    // write a (layout [n][s][k], float4 x4)
    float4* ap = (float4*)(aT + ((size_t)(n * SPIX + s)) * KCL + kg * 16);
    #pragma unroll
    for (int j = 0; j < 4; j++) {
        float4 v; v.x = acc[4*j+0]; v.y = acc[4*j+1]; v.z = acc[4*j+2]; v.w = acc[4*j+3];
        ap[j] = v;
    }

    // asum partial: reduce over the 64 pixels (lanes) of this wave
    #pragma unroll
    for (int i = 0; i < 16; i++) {
        float v = acc[i];
        #pragma unroll
        for (int off = 32; off > 0; off >>= 1) v += __shfl_xor(v, off, 64);
        if (p == 0) asum_part[blk * KCL + kg * 16 + i] = v;
    }
}

// ---------------- K3: vlad partials: vlad_part[blk][k][c] -------------------
// grid 512 = (n, 16 chunks of 256 px), 1024 threads = (kg = tid>>8, c = tid&255)
// acc[16] per thread; x staged in LDS (padded, conflict-free), reused by 4 kgs.
__global__ __launch_bounds__(1024) void k_vlad(const float* __restrict__ x,
                                               const float* __restrict__ inv_norm,
                                               const float* __restrict__ aT,
                                               float* __restrict__ vlad_part) {
    int blk = blockIdx.x;
    int n = blk >> 4, ch = blk & 15;
    int s0 = ch * 256;
    __shared__ float xt[64 * 257];  // [pixel][channel], padded
    int tid = threadIdx.x;
    int c = tid & 255, kg = tid >> 8;          // wave-uniform kg (wave>>2)
    int pw = tid & 63, wrow = tid >> 6;        // staging map

    float acc[16];
    #pragma unroll
    for (int i = 0; i < 16; i++) acc[i] = 0.f;

    for (int t = 0; t < 4; t++) {
        int sb = s0 + t * 64;
        float invp = inv_norm[n * SPIX + sb + pw];
        __syncthreads();
        #pragma unroll
        for (int i = 0; i < 16; i++) {
            int cc = wrow + i * 16;
            float xv = x[((size_t)n * CDIM + cc) * SPIX + sb + pw];  // coalesced
            xt[pw * 257 + cc] = xv * invp;
        }
        __syncthreads();
        const float* ab = aT + ((size_t)(n * SPIX + sb)) * KCL + kg * 16;
        for (int pp = 0; pp < 64; pp++) {
            float xn = xt[pp * 257 + c];               // lanes stride-1: conflict-free
            const float4* ap = (const float4*)(ab + (size_t)pp * KCL);  // wave-uniform
            #pragma unroll
            for (int q = 0; q < 4; q++) {
                float4 a4 = ap[q];
                acc[4*q+0] = fmaf(a4.x, xn, acc[4*q+0]);
                acc[4*q+1] = fmaf(a4.y, xn, acc[4*q+1]);
                acc[4*q+2] = fmaf(a4.z, xn, acc[4*q+2]);
                acc[4*q+3] = fmaf(a4.w, xn, acc[4*q+3]);
            }
        }
    }
    float* vp = vlad_part + (size_t)blk * KCL * CDIM + (size_t)(kg * 16) * CDIM + c;
    #pragma unroll
    for (int i = 0; i < 16; i++) vp[(size_t)i * CDIM] = acc[i];  // coalesced rows
}

// ---------------- K4: combine partials + centroid subtract + intra-norm ----
// grid 2048 = (n,k), 256 threads (c = tid)
__global__ __launch_bounds__(256) void k_combine(const float* __restrict__ vlad_part,
                                                 const float* __restrict__ asum_part,
                                                 const float* __restrict__ cent,
                                                 float* __restrict__ out,
                                                 float* __restrict__ rs) {
    int blk = blockIdx.x;          // n*64 + k
    int n = blk >> 6, k = blk & 63;
    int c = threadIdx.x;
    float v = 0.f;
    for (int j = 0; j < 16; j++)
        v += vlad_part[(((size_t)(n * 16 + j)) * KCL + k) * CDIM + c];
    float as = 0.f;
    for (int j = 0; j < 64; j++)
        as += asum_part[(n * 64 + j) * KCL + k];
    v = fmaf(-as, cent[k * CDIM + c], v);

    float t = v * v;
    #pragma unroll
    for (int off = 32; off > 0; off >>= 1) t += __shfl_xor(t, off, 64);
    __shared__ float w4[4];
    int lane = threadIdx.x & 63, wid = threadIdx.x >> 6;
    if (lane == 0) w4[wid] = t;
    __syncthreads();
    float ss = w4[0] + w4[1] + w4[2] + w4[3];
    float inv = 1.0f / fmaxf(sqrtf(ss), 1e-12f);
    out[(size_t)blk * CDIM + c] = v * inv;
    if (threadIdx.x == 0) rs[blk] = ss * inv * inv;
}

// ---------------- K5: global L2 normalize per image (in place) --------------
// grid 256 = (n, 8), 256 threads
__global__ __launch_bounds__(256) void k_gnorm(const float* __restrict__ rs,
                                               float* __restrict__ out) {
    int n = blockIdx.x >> 3, j = blockIdx.x & 7;
    float ss = 0.f;
    for (int k = 0; k < KCL; k++) ss += rs[n * KCL + k];
    float g = 1.0f / fmaxf(sqrtf(ss), 1e-12f);
    size_t base = (size_t)n * (KCL * CDIM) + j * 2048 + threadIdx.x;
    for (int i = 0; i < 8; i++) out[base + i * 256] *= g;
}

extern "C" void kernel_launch(void* const* d_in, const int* in_sizes, int n_in,
                              void* d_out, int out_size, void* d_ws, size_t ws_size,
                              hipStream_t stream) {
    const float* x    = (const float*)d_in[0];   // [32][256][64][64]
    const float* w    = (const float*)d_in[1];   // [64][256]
    const float* b    = (const float*)d_in[2];   // [64]
    const float* cent = (const float*)d_in[3];   // [64][256]
    float* out = (float*)d_out;

    float* ws = (float*)d_ws;
    float* wT        = ws;                        // 16384
    float* inv_norm  = wT + 16384;                // 131072
    float* aT        = inv_norm + 131072;         // 32*4096*64 = 8388608
    float* vlad_part = aT + 8388608;              // 512*64*256 = 8388608
    float* asum_part = vlad_part + 8388608;       // 2048*64 = 131072
    float* rs        = asum_part + 131072;        // 2048

    k_wt<<<64, 256, 0, stream>>>(w, wT);
    k_logits<<<2048, 256, 0, stream>>>(x, wT, b, aT, inv_norm, asum_part);
    k_vlad<<<512, 1024, 0, stream>>>(x, inv_norm, aT, vlad_part);
    k_combine<<<2048, 256, 0, stream>>>(vlad_part, asum_part, cent, out, rs);
    k_gnorm<<<256, 256, 0, stream>>>(rs, out);
}

// Round 4
// 211.859 us; speedup vs baseline: 2.5117x; 2.5117x over previous
//
#include <hip/hip_runtime.h>
#include <math.h>

#define NIMG 32
#define CDIM 256
#define KCL  64
#define SPIX 4096

// ---------------- K0: transpose conv_w (K x C) -> wT (C x K) ----------------
__global__ __launch_bounds__(256) void k_wt(const float* __restrict__ w, float* __restrict__ wT) {
    int g = blockIdx.x * 256 + threadIdx.x;   // g = k*CDIM + c
    if (g < KCL * CDIM) {
        int k = g / CDIM, c = g % CDIM;
        wT[c * KCL + k] = w[g];
    }
}

// ---------------- K1: fused norm + logits + softmax + asum ------------------
// grid 512 = (n, 16 chunks of 256 px), 512 threads = (kh = tid>>8, s = tid&255)
// w staged in LDS once (64 KB): inner loop reads are wave-uniform ds_read_b128
// broadcasts, NOT per-lane L2 loads (rounds 1-3: w streamed from L2 every
// iteration -> latency-bound at 12-18% VALUBusy). acc[32]/thread.
__global__ __launch_bounds__(512, 4) void k_logits(const float* __restrict__ x,
                                                   const float* __restrict__ wT,
                                                   const float* __restrict__ b,
                                                   float* __restrict__ aT,
                                                   float* __restrict__ inv_norm,
                                                   float* __restrict__ asum_part) {
    int blk = blockIdx.x;
    int n = blk >> 4, ch = blk & 15;
    int tid = threadIdx.x;
    int kh = tid >> 8, sl = tid & 255;
    int s = ch * 256 + sl;

    __shared__ float wlds[256 * 64];   // [c][k], linear copy of wT: no conflicts
    __shared__ float red[512];

    {   // stage wT -> LDS, fully coalesced, 32 floats/thread
        const float4* wsrc = (const float4*)wT;
        float4* wdst = (float4*)wlds;
        #pragma unroll
        for (int i = 0; i < 8; i++) wdst[i * 512 + tid] = wsrc[i * 512 + tid];
    }
    __syncthreads();

    const float* xp = x + ((size_t)n * CDIM) * SPIX + s;
    float acc[32];
    #pragma unroll
    for (int i = 0; i < 32; i++) acc[i] = 0.f;
    float nrm = 0.f;

    for (int c = 0; c < CDIM; c++) {
        float xv = xp[(size_t)c * SPIX];                       // coalesced global
        nrm = fmaf(xv, xv, nrm);
        const float4* wc = (const float4*)(wlds + c * 64 + kh * 32);  // uniform bcast
        #pragma unroll
        for (int j = 0; j < 8; j++) {
            float4 wv = wc[j];
            acc[4*j+0] = fmaf(wv.x, xv, acc[4*j+0]);
            acc[4*j+1] = fmaf(wv.y, xv, acc[4*j+1]);
            acc[4*j+2] = fmaf(wv.z, xv, acc[4*j+2]);
            acc[4*j+3] = fmaf(wv.w, xv, acc[4*j+3]);
        }
    }

    float invn = 1.0f / fmaxf(sqrtf(nrm), 1e-12f);
    if (kh == 0) inv_norm[n * SPIX + s] = invn;

    // logits = acc*invn + b; softmax over 64 k = 2 kh halves via LDS
    const float4* b4 = (const float4*)b + kh * 8;
    float m = -1e30f;
    #pragma unroll
    for (int j = 0; j < 8; j++) {
        float4 bv = b4[j];
        acc[4*j+0] = fmaf(acc[4*j+0], invn, bv.x);
        acc[4*j+1] = fmaf(acc[4*j+1], invn, bv.y);
        acc[4*j+2] = fmaf(acc[4*j+2], invn, bv.z);
        acc[4*j+3] = fmaf(acc[4*j+3], invn, bv.w);
    }
    #pragma unroll
    for (int i = 0; i < 32; i++) m = fmaxf(m, acc[i]);
    red[tid] = m;
    __syncthreads();
    m = fmaxf(red[sl], red[256 + sl]);
    float ssum = 0.f;
    #pragma unroll
    for (int i = 0; i < 32; i++) { float e = __expf(acc[i] - m); acc[i] = e; ssum += e; }
    __syncthreads();
    red[tid] = ssum;
    __syncthreads();
    float r = 1.0f / (red[sl] + red[256 + sl]);
    #pragma unroll
    for (int i = 0; i < 32; i++) acc[i] *= r;

    // write a: layout [n][s][64], 8 float4 per thread
    float4* ap = (float4*)(aT + ((size_t)(n * SPIX + s)) * KCL + kh * 32);
    #pragma unroll
    for (int j = 0; j < 8; j++) {
        float4 v; v.x = acc[4*j+0]; v.y = acc[4*j+1]; v.z = acc[4*j+2]; v.w = acc[4*j+3];
        ap[j] = v;
    }

    // asum partials: reduce over 64 lanes (= 64 pixels) per wave
    int wv = tid >> 6, lane = tid & 63;
    #pragma unroll
    for (int i = 0; i < 32; i++) {
        float v = acc[i];
        #pragma unroll
        for (int off = 32; off > 0; off >>= 1) v += __shfl_xor(v, off, 64);
        if (lane == 0) asum_part[(blk * 8 + wv) * 32 + i] = v;
    }
}

// ---------------- K2: vlad partials ----------------------------------------
// grid 512 = (n, 16 groups of 256 px), 512 threads = (kh = tid>>8, c = tid&255)
// 8 chunks of 32 px; x-tile [c][s] (pad 33) + a-tile [s][k] staged in LDS.
// acc[32] = 32 k for this thread's channel c, accumulated across all chunks.
__global__ __launch_bounds__(512, 4) void k_vlad(const float* __restrict__ x,
                                                 const float* __restrict__ inv_norm,
                                                 const float* __restrict__ aT,
                                                 float* __restrict__ vlad_part) {
    int blk = blockIdx.x;
    int n = blk >> 4, g = blk & 15;
    int tid = threadIdx.x;
    int kh = tid >> 8, c = tid & 255;

    __shared__ float xt[256 * 33];   // [c][s], pad: read lanes c-consecutive -> conflict-free
    __shared__ float at[32 * 64];    // [s][k]

    float acc[32];
    #pragma unroll
    for (int i = 0; i < 32; i++) acc[i] = 0.f;

    int sl = tid & 31;       // staging pixel 0..31
    int cr = tid >> 5;       // staging row 0..15

    for (int t = 0; t < 8; t++) {
        int s0 = g * 256 + t * 32;
        float invp = inv_norm[n * SPIX + s0 + sl];
        __syncthreads();   // previous chunk's reads done before overwrite
        #pragma unroll
        for (int i = 0; i < 16; i++) {
            int cc = cr + i * 16;
            xt[cc * 33 + sl] = x[((size_t)n * CDIM + cc) * SPIX + s0 + sl] * invp;
        }
        ((float4*)at)[tid] = ((const float4*)(aT + ((size_t)(n * SPIX + s0)) * KCL))[tid];
        __syncthreads();

        const float* ab = at + kh * 32;
        for (int ss = 0; ss < 32; ss++) {
            float xn = xt[c * 33 + ss];                      // conflict-free
            const float4* ap = (const float4*)(ab + ss * 64); // uniform bcast
            #pragma unroll
            for (int q = 0; q < 8; q++) {
                float4 a4 = ap[q];
                acc[4*q+0] = fmaf(a4.x, xn, acc[4*q+0]);
                acc[4*q+1] = fmaf(a4.y, xn, acc[4*q+1]);
                acc[4*q+2] = fmaf(a4.z, xn, acc[4*q+2]);
                acc[4*q+3] = fmaf(a4.w, xn, acc[4*q+3]);
            }
        }
    }
    float* vp = vlad_part + ((size_t)blk * KCL + kh * 32) * CDIM + c;
    #pragma unroll
    for (int i = 0; i < 32; i++) vp[(size_t)i * CDIM] = acc[i];   // coalesced
}

// ---------------- K4: combine partials + centroid subtract + intra-norm ----
// grid 2048 = (n,k), 256 threads (c = tid)
__global__ __launch_bounds__(256) void k_combine(const float* __restrict__ vlad_part,
                                                 const float* __restrict__ asum_part,
                                                 const float* __restrict__ cent,
                                                 float* __restrict__ out,
                                                 float* __restrict__ rs) {
    int blk = blockIdx.x;          // n*64 + k
    int n = blk >> 6, k = blk & 63;
    int c = threadIdx.x;
    float v = 0.f;
    for (int j = 0; j < 16; j++)
        v += vlad_part[(((size_t)(n * 16 + j)) * KCL + k) * CDIM + c];
    float as = 0.f;
    int kh = k >> 5, kj = k & 31;
    for (int j = 0; j < 16; j++)
        for (int q = 0; q < 4; q++)
            as += asum_part[(((n * 16 + j) * 8) + kh * 4 + q) * 32 + kj];
    v = fmaf(-as, cent[k * CDIM + c], v);

    float t = v * v;
    #pragma unroll
    for (int off = 32; off > 0; off >>= 1) t += __shfl_xor(t, off, 64);
    __shared__ float w4[4];
    int lane = threadIdx.x & 63, wid = threadIdx.x >> 6;
    if (lane == 0) w4[wid] = t;
    __syncthreads();
    float ss = w4[0] + w4[1] + w4[2] + w4[3];
    float inv = 1.0f / fmaxf(sqrtf(ss), 1e-12f);
    out[(size_t)blk * CDIM + c] = v * inv;
    if (threadIdx.x == 0) rs[blk] = ss * inv * inv;
}

// ---------------- K5: global L2 normalize per image (in place) --------------
// grid 256 = (n, 8), 256 threads
__global__ __launch_bounds__(256) void k_gnorm(const float* __restrict__ rs,
                                               float* __restrict__ out) {
    int n = blockIdx.x >> 3, j = blockIdx.x & 7;
    float ss = 0.f;
    for (int k = 0; k < KCL; k++) ss += rs[n * KCL + k];
    float g = 1.0f / fmaxf(sqrtf(ss), 1e-12f);
    size_t base = (size_t)n * (KCL * CDIM) + j * 2048 + threadIdx.x;
    for (int i = 0; i < 8; i++) out[base + i * 256] *= g;
}

extern "C" void kernel_launch(void* const* d_in, const int* in_sizes, int n_in,
                              void* d_out, int out_size, void* d_ws, size_t ws_size,
                              hipStream_t stream) {
    const float* x    = (const float*)d_in[0];   // [32][256][64][64]
    const float* w    = (const float*)d_in[1];   // [64][256]
    const float* b    = (const float*)d_in[2];   // [64]
    const float* cent = (const float*)d_in[3];   // [64][256]
    float* out = (float*)d_out;

    float* ws = (float*)d_ws;
    float* wT        = ws;                        // 16384
    float* inv_norm  = wT + 16384;                // 131072
    float* aT        = inv_norm + 131072;         // 32*4096*64 = 8388608
    float* vlad_part = aT + 8388608;              // 512*64*256 = 8388608
    float* asum_part = vlad_part + 8388608;       // 512*8*32 = 131072
    float* rs        = asum_part + 131072;        // 2048

    k_wt<<<64, 256, 0, stream>>>(w, wT);
    k_logits<<<512, 512, 0, stream>>>(x, wT, b, aT, inv_norm, asum_part);
    k_vlad<<<512, 512, 0, stream>>>(x, inv_norm, aT, vlad_part);
    k_combine<<<2048, 256, 0, stream>>>(vlad_part, asum_part, cent, out, rs);
    k_gnorm<<<256, 256, 0, stream>>>(rs, out);
}

// Round 5
// 170.035 us; speedup vs baseline: 3.1295x; 1.2460x over previous
//
#include <hip/hip_runtime.h>
#include <math.h>

#define NIMG 32
#define CDIM 256
#define KCL  64
#define SPIX 4096

// ---------------- K0: transpose conv_w (K x C) -> wT (C x K) ----------------
__global__ __launch_bounds__(256) void k_wt(const float* __restrict__ w, float* __restrict__ wT) {
    int g = blockIdx.x * 256 + threadIdx.x;   // g = k*CDIM + c
    if (g < KCL * CDIM) {
        int k = g / CDIM, c = g % CDIM;
        wT[c * KCL + k] = w[g];
    }
}

// ---------------- K1: fused norm + logits + softmax + asum ------------------
// grid 512 = (n, 16 chunks of 256 px), 512 threads = (kh = tid>>8, s = tid&255)
// w is read at a readfirstlane-uniform address straight from global -> compiler
// scalarizes to s_load (SMEM/K$ pipe, SGPR operands in v_fma). Round 4 put w
// in LDS: 8 broadcast ds_read_b128 per wave per c = ~6x LDS-pipe oversubscription
// vs VALU (VALUBusy 30%). Inner loop now has ZERO LDS traffic.
__global__ __launch_bounds__(512, 4) void k_logits(const float* __restrict__ x,
                                                   const float* __restrict__ wT,
                                                   const float* __restrict__ b,
                                                   float* __restrict__ aT,
                                                   float* __restrict__ inv_norm,
                                                   float* __restrict__ asum_part) {
    int blk = blockIdx.x;
    int n = blk >> 4, ch = blk & 15;
    int tid = threadIdx.x;
    int kh = __builtin_amdgcn_readfirstlane(tid >> 8);   // wave-uniform, in SGPR
    int sl = tid & 255;
    int s = ch * 256 + sl;

    __shared__ float red[512];

    const float* xp = x + ((size_t)n * CDIM) * SPIX + s;
    const float* wbase = wT + kh * 32;                   // uniform base

    float acc[32];
    #pragma unroll
    for (int i = 0; i < 32; i++) acc[i] = 0.f;
    float nrm = 0.f;

    for (int c = 0; c < CDIM; c++) {
        float xv = xp[(size_t)c * SPIX];                 // coalesced per-lane global
        nrm = fmaf(xv, xv, nrm);
        const float4* wc = (const float4*)(wbase + c * 64);  // uniform -> s_load
        #pragma unroll
        for (int j = 0; j < 8; j++) {
            float4 wv = wc[j];
            acc[4*j+0] = fmaf(wv.x, xv, acc[4*j+0]);
            acc[4*j+1] = fmaf(wv.y, xv, acc[4*j+1]);
            acc[4*j+2] = fmaf(wv.z, xv, acc[4*j+2]);
            acc[4*j+3] = fmaf(wv.w, xv, acc[4*j+3]);
        }
    }

    float invn = 1.0f / fmaxf(sqrtf(nrm), 1e-12f);
    if (kh == 0) inv_norm[n * SPIX + s] = invn;

    // logits = acc*invn + b; softmax over 64 k = 2 kh halves via LDS
    const float4* b4 = (const float4*)b + kh * 8;
    float m = -1e30f;
    #pragma unroll
    for (int j = 0; j < 8; j++) {
        float4 bv = b4[j];
        acc[4*j+0] = fmaf(acc[4*j+0], invn, bv.x);
        acc[4*j+1] = fmaf(acc[4*j+1], invn, bv.y);
        acc[4*j+2] = fmaf(acc[4*j+2], invn, bv.z);
        acc[4*j+3] = fmaf(acc[4*j+3], invn, bv.w);
    }
    #pragma unroll
    for (int i = 0; i < 32; i++) m = fmaxf(m, acc[i]);
    red[tid] = m;
    __syncthreads();
    m = fmaxf(red[sl], red[256 + sl]);
    float ssum = 0.f;
    #pragma unroll
    for (int i = 0; i < 32; i++) { float e = __expf(acc[i] - m); acc[i] = e; ssum += e; }
    __syncthreads();
    red[tid] = ssum;
    __syncthreads();
    float r = 1.0f / (red[sl] + red[256 + sl]);
    #pragma unroll
    for (int i = 0; i < 32; i++) acc[i] *= r;

    // write a: layout [n][s][64], 8 float4 per thread
    float4* ap = (float4*)(aT + ((size_t)(n * SPIX + s)) * KCL + kh * 32);
    #pragma unroll
    for (int j = 0; j < 8; j++) {
        float4 v; v.x = acc[4*j+0]; v.y = acc[4*j+1]; v.z = acc[4*j+2]; v.w = acc[4*j+3];
        ap[j] = v;
    }

    // asum partials: reduce over 64 lanes (= 64 pixels) per wave
    int wv = tid >> 6, lane = tid & 63;
    #pragma unroll
    for (int i = 0; i < 32; i++) {
        float v = acc[i];
        #pragma unroll
        for (int off = 32; off > 0; off >>= 1) v += __shfl_xor(v, off, 64);
        if (lane == 0) asum_part[(blk * 8 + wv) * 32 + i] = v;
    }
}

// ---------------- K2: vlad partials ----------------------------------------
// grid 512 = (n, 16 groups of 256 px), 512 threads = (kh = tid>>8, c = tid&255)
// a-slice read at readfirstlane-uniform address from global (s_load) instead of
// the round-4 LDS broadcast tile (8 ds_read_b128/wave/ss -> LDS-pipe-bound).
// x-tile stays in LDS: per-lane conflict-free b32 (5.8 cyc << 64 cyc VALU).
__global__ __launch_bounds__(512, 4) void k_vlad(const float* __restrict__ x,
                                                 const float* __restrict__ inv_norm,
                                                 const float* __restrict__ aT,
                                                 float* __restrict__ vlad_part) {
    int blk = blockIdx.x;
    int n = blk >> 4, g = blk & 15;
    int tid = threadIdx.x;
    int kh = __builtin_amdgcn_readfirstlane(tid >> 8);   // wave-uniform
    int c = tid & 255;

    __shared__ float xt[256 * 33];   // [c][s32], pad 33: conflict-free per-lane reads

    float acc[32];
    #pragma unroll
    for (int i = 0; i < 32; i++) acc[i] = 0.f;

    int sl = tid & 31;       // staging pixel 0..31
    int cr = tid >> 5;       // staging row 0..15

    for (int t = 0; t < 8; t++) {
        int s0 = g * 256 + t * 32;
        float invp = inv_norm[n * SPIX + s0 + sl];
        __syncthreads();   // previous chunk's reads done before overwrite
        #pragma unroll
        for (int i = 0; i < 16; i++) {
            int cc = cr + i * 16;
            xt[cc * 33 + sl] = x[((size_t)n * CDIM + cc) * SPIX + s0 + sl] * invp;
        }
        __syncthreads();

        const float* ab = aT + ((size_t)(n * SPIX + s0)) * KCL + kh * 32;  // uniform
        for (int ss = 0; ss < 32; ss++) {
            float xn = xt[c * 33 + ss];                       // per-lane, conflict-free
            const float4* ap = (const float4*)(ab + ss * 64); // uniform -> s_load
            #pragma unroll
            for (int q = 0; q < 8; q++) {
                float4 a4 = ap[q];
                acc[4*q+0] = fmaf(a4.x, xn, acc[4*q+0]);
                acc[4*q+1] = fmaf(a4.y, xn, acc[4*q+1]);
                acc[4*q+2] = fmaf(a4.z, xn, acc[4*q+2]);
                acc[4*q+3] = fmaf(a4.w, xn, acc[4*q+3]);
            }
        }
    }
    float* vp = vlad_part + ((size_t)blk * KCL + kh * 32) * CDIM + c;
    #pragma unroll
    for (int i = 0; i < 32; i++) vp[(size_t)i * CDIM] = acc[i];   // coalesced
}

// ---------------- K4: combine partials + centroid subtract + intra-norm ----
// grid 2048 = (n,k), 256 threads (c = tid)
__global__ __launch_bounds__(256) void k_combine(const float* __restrict__ vlad_part,
                                                 const float* __restrict__ asum_part,
                                                 const float* __restrict__ cent,
                                                 float* __restrict__ out,
                                                 float* __restrict__ rs) {
    int blk = blockIdx.x;          // n*64 + k
    int n = blk >> 6, k = blk & 63;
    int c = threadIdx.x;
    float v = 0.f;
    for (int j = 0; j < 16; j++)
        v += vlad_part[(((size_t)(n * 16 + j)) * KCL + k) * CDIM + c];
    float as = 0.f;
    int kh = k >> 5, kj = k & 31;
    for (int j = 0; j < 16; j++)
        for (int q = 0; q < 4; q++)
            as += asum_part[(((n * 16 + j) * 8) + kh * 4 + q) * 32 + kj];
    v = fmaf(-as, cent[k * CDIM + c], v);

    float t = v * v;
    #pragma unroll
    for (int off = 32; off > 0; off >>= 1) t += __shfl_xor(t, off, 64);
    __shared__ float w4[4];
    int lane = threadIdx.x & 63, wid = threadIdx.x >> 6;
    if (lane == 0) w4[wid] = t;
    __syncthreads();
    float ss = w4[0] + w4[1] + w4[2] + w4[3];
    float inv = 1.0f / fmaxf(sqrtf(ss), 1e-12f);
    out[(size_t)blk * CDIM + c] = v * inv;
    if (threadIdx.x == 0) rs[blk] = ss * inv * inv;
}

// ---------------- K5: global L2 normalize per image (in place) --------------
// grid 256 = (n, 8), 256 threads
__global__ __launch_bounds__(256) void k_gnorm(const float* __restrict__ rs,
                                               float* __restrict__ out) {
    int n = blockIdx.x >> 3, j = blockIdx.x & 7;
    float ss = 0.f;
    for (int k = 0; k < KCL; k++) ss += rs[n * KCL + k];
    float g = 1.0f / fmaxf(sqrtf(ss), 1e-12f);
    size_t base = (size_t)n * (KCL * CDIM) + j * 2048 + threadIdx.x;
    for (int i = 0; i < 8; i++) out[base + i * 256] *= g;
}

extern "C" void kernel_launch(void* const* d_in, const int* in_sizes, int n_in,
                              void* d_out, int out_size, void* d_ws, size_t ws_size,
                              hipStream_t stream) {
    const float* x    = (const float*)d_in[0];   // [32][256][64][64]
    const float* w    = (const float*)d_in[1];   // [64][256]
    const float* b    = (const float*)d_in[2];   // [64]
    const float* cent = (const float*)d_in[3];   // [64][256]
    float* out = (float*)d_out;

    float* ws = (float*)d_ws;
    float* wT        = ws;                        // 16384
    float* inv_norm  = wT + 16384;                // 131072
    float* aT        = inv_norm + 131072;         // 32*4096*64 = 8388608
    float* vlad_part = aT + 8388608;              // 512*64*256 = 8388608
    float* asum_part = vlad_part + 8388608;       // 512*8*32 = 131072
    float* rs        = asum_part + 131072;        // 2048

    k_wt<<<64, 256, 0, stream>>>(w, wT);
    k_logits<<<512, 512, 0, stream>>>(x, wT, b, aT, inv_norm, asum_part);
    k_vlad<<<512, 512, 0, stream>>>(x, inv_norm, aT, vlad_part);
    k_combine<<<2048, 256, 0, stream>>>(vlad_part, asum_part, cent, out, rs);
    k_gnorm<<<256, 256, 0, stream>>>(rs, out);
}